// Round 7
// baseline (120.775 us; speedup 1.0000x reference)
//
#include <hip/hip_runtime.h>

// Problem constants
#define BATCH  4
#define SEQL   2048
#define DMODEL 1024
#define CT     64            // chunk length
#define NCH    (SEQL / CT)   // 32 chunks

// ws layout (float offsets). ws_size = 256 MiB, we use ~8.5 MiB.
#define WS_W     1024        // W[tau][m] = (B^T A^(tau+1))[m]  : 64*16
#define WS_KV    2048        // kvext; kvext[63+d] = B^T A^d B (d=0..63)
#define WS_APOW  2176        // Apow[m][k] = (A^64)[m][k]       : 256
#define WS_HIN   4096        // hin[b][j][d][m] = s_{j-1}       : B*NCH*D*16
#define WS_CBUF  (WS_HIN + BATCH * NCH * DMODEL * 16)   // c[b][j][d][m]

// ---------------------------------------------------------------------------
// K1': fused tables + chunk-state. 512 blocks x 256 threads (2 blocks/CU).
// Structure: (1) issue first x batch (8 loads) -> (2) fp64 table doubling
// (proven KA code; ~0.5 us, hides under the x HBM latency) -> (3) write
// W/kv/Apow tables to ws (redundant across blocks, benign) -> (4) proven
// R0 K1 streaming body, P read from LDS via same-address float4 broadcasts.
//   c_j[m] = sum_sigma P[sigma][m] x[sigma],  P[sigma] = A^(63-sigma) B
// ---------------------------------------------------------------------------
__global__ __launch_bounds__(256) void k1_tables_chunkstate(const float* __restrict__ x,
                                                            const float* __restrict__ Ain,
                                                            const float* __restrict__ Bvin,
                                                            float* __restrict__ ws) {
    __shared__ double M[256], Mt[256];     // A^(2^k), scratch
    __shared__ double Vd[64][16];          // v_d = A^d B
    __shared__ double Wd[65][16];          // w_d = B^T A^d
    __shared__ double bd[16];
    __shared__ __align__(16) float Pl[64][16];   // P[sigma][m] fp32

    const int t    = threadIdx.x;
    const int blk  = blockIdx.x;          // 512 blocks
    const int b    = blk >> 7;
    const int j    = (blk >> 2) & 31;
    const int dblk = blk & 3;
    const int d    = dblk * 256 + t;

    const float* xp = x + ((size_t)(b * SEQL + j * CT)) * DMODEL + d;

    // (1) first x batch issues NOW; consumed after phase T (waitcnt there)
    float xa[8], xb[8];
    #pragma unroll
    for (int s = 0; s < 8; ++s) xa[s] = xp[(size_t)s * DMODEL];

    // (2) phase T: fp64 log-depth doubling (proven KA code)
    M[t] = (double)Ain[t];
    if (t < 16) {
        bd[t]    = (double)Bvin[t];
        Vd[0][t] = (double)Bvin[t];        // v_0 = B
        Wd[0][t] = (double)Bvin[t];        // w_0 = B^T
    }
    __syncthreads();

    #pragma unroll
    for (int k = 0; k < 6; ++k) {          // M = A^(2^k) entering round k
        const int cnt = 1 << k;
        const int mm  = t & 15;
        for (int dd = t >> 4; dd < cnt; dd += 16) {
            double av = 0.0, aw = 0.0;
            #pragma unroll
            for (int l = 0; l < 16; ++l) {
                av += M[mm * 16 + l] * Vd[dd][l];
                aw += Wd[dd][l] * M[l * 16 + mm];
            }
            Vd[dd + cnt][mm] = av;
            Wd[dd + cnt][mm] = aw;
        }
        __syncthreads();
        {
            const int i = t >> 4, jj = t & 15;
            double acc = 0.0;
            #pragma unroll
            for (int l = 0; l < 16; ++l) acc += M[i * 16 + l] * M[l * 16 + jj];
            Mt[t] = acc;
            if (k == 5 && t < 16) {
                double aw = 0.0;
                #pragma unroll
                for (int l = 0; l < 16; ++l) aw += Wd[32][l] * M[l * 16 + t];
                Wd[64][t] = aw;
            }
        }
        __syncthreads();
        M[t] = Mt[t];
        __syncthreads();
    }
    // M = A^64; Vd[0..63], Wd[0..64] complete.

    // (3) fp32 tables: Pl to LDS; W/kv/Apow to ws (all blocks, same values)
    for (int e = t; e < 1024; e += 256) {
        const int r = e >> 4, mm = e & 15;
        Pl[r][mm] = (float)Vd[63 - r][mm];           // P[sigma][m]
        ws[WS_W + e] = (float)Wd[r + 1][mm];         // W[tau][m]
    }
    ws[WS_APOW + t] = (float)M[t];                   // A^64
    if (t < 64) {                                    // kv[d] = B^T A^d B
        double kd = 0.0;
        #pragma unroll
        for (int q = 0; q < 16; ++q) kd += bd[q] * Vd[t][q];
        ws[WS_KV + 63 + t] = (float)kd;
    }
    __syncthreads();                                 // Pl ready

    // (4) proven K1 streaming body; P via LDS float4 broadcasts
    float c[16];
    #pragma unroll
    for (int m = 0; m < 16; ++m) c[m] = 0.0f;

    #pragma unroll
    for (int g = 0; g < 8; ++g) {          // 8 batches of 8 sigma
        float* cur = (g & 1) ? xb : xa;
        float* nxt = (g & 1) ? xa : xb;
        if (g < 7) {
            #pragma unroll
            for (int s = 0; s < 8; ++s)
                nxt[s] = xp[(size_t)((g + 1) * 8 + s) * DMODEL];
        }
        #pragma unroll
        for (int s = 0; s < 8; ++s) {
            const int ss = g * 8 + s;
            const float xv = cur[s];
            const float4 p0 = *(const float4*)(&Pl[ss][0]);
            const float4 p1 = *(const float4*)(&Pl[ss][4]);
            const float4 p2 = *(const float4*)(&Pl[ss][8]);
            const float4 p3 = *(const float4*)(&Pl[ss][12]);
            c[0]  = fmaf(p0.x, xv, c[0]);  c[1]  = fmaf(p0.y, xv, c[1]);
            c[2]  = fmaf(p0.z, xv, c[2]);  c[3]  = fmaf(p0.w, xv, c[3]);
            c[4]  = fmaf(p1.x, xv, c[4]);  c[5]  = fmaf(p1.y, xv, c[5]);
            c[6]  = fmaf(p1.z, xv, c[6]);  c[7]  = fmaf(p1.w, xv, c[7]);
            c[8]  = fmaf(p2.x, xv, c[8]);  c[9]  = fmaf(p2.y, xv, c[9]);
            c[10] = fmaf(p2.z, xv, c[10]); c[11] = fmaf(p2.w, xv, c[11]);
            c[12] = fmaf(p3.x, xv, c[12]); c[13] = fmaf(p3.y, xv, c[13]);
            c[14] = fmaf(p3.z, xv, c[14]); c[15] = fmaf(p3.w, xv, c[15]);
        }
    }

    float4* outp = (float4*)(ws + WS_CBUF + (((size_t)(b * NCH + j) * DMODEL) + d) * 16);
    #pragma unroll
    for (int q = 0; q < 4; ++q)
        outp[q] = make_float4(c[4 * q], c[4 * q + 1], c[4 * q + 2], c[4 * q + 3]);
}

// ---------------------------------------------------------------------------
// K2: carry scan over chunks (proven R0-R3 body). Thread = (channel, m).
// All 32 chunk partials prefetched upfront (~8 MB in flight grid-wide),
// then the serial shfl chain runs from registers.
// s_j = Apow*s_{j-1} + c_j ; hin_j = s_{j-1}.
// ---------------------------------------------------------------------------
__global__ __launch_bounds__(256) void k2_carry(float* __restrict__ ws) {
    const int blk = blockIdx.x;           // 256 blocks
    const int b   = blk >> 6;
    const int d0  = (blk & 63) * 16;
    const int t   = threadIdx.x;
    const int m   = t & 15;
    const int ch  = t >> 4;
    const int d   = d0 + ch;
    const int laneBase = t & 48;          // 16-lane group base within wave

    const float* cbuf    = ws + WS_CBUF;
    const size_t base0   = (((size_t)(b * NCH) * DMODEL) + d) * 16 + m;
    const size_t jstride = (size_t)DMODEL * 16;

    float cpre[NCH];
    #pragma unroll
    for (int j = 0; j < NCH; ++j)
        cpre[j] = cbuf[base0 + (size_t)j * jstride];

    float Arow[16];
    #pragma unroll
    for (int k = 0; k < 16; ++k) Arow[k] = ws[WS_APOW + m * 16 + k];

    float* hin = ws + WS_HIN;
    float s = 0.0f;
    #pragma unroll
    for (int j = 0; j < NCH; ++j) {
        hin[base0 + (size_t)j * jstride] = s;
        float acc = cpre[j];
        #pragma unroll
        for (int k = 0; k < 16; ++k)
            acc = fmaf(Arow[k], __shfl(s, laneBase + k, 64), acc);
        s = acc;
    }
}

// ---------------------------------------------------------------------------
// K3: proven round-6 version, unchanged. 2048 blocks, (256,4) = 128-VGPR
// budget (no spill), 16 KiB LDS tile, all 64 taus per tile.
//   y[tau] = W[tau].h_in + sum_{s<=tau} kv[tau-s] x[s]
// ---------------------------------------------------------------------------
template <int TT>
__device__ __forceinline__ void k3_body(const float* __restrict__ xs,
                                        const float* __restrict__ ws,
                                        float* __restrict__ y,
                                        int b, int j, int d, int dl) {
    const float* hinp = ws + WS_HIN + (((size_t)(b * NCH + j) * DMODEL) + d) * 16;
    float4 hv[4];
    #pragma unroll
    for (int q = 0; q < 4; ++q) hv[q] = ((const float4*)hinp)[q];

    float h[16];
    #pragma unroll
    for (int q = 0; q < 4; ++q) {
        h[4 * q]     = hv[q].x; h[4 * q + 1] = hv[q].y;
        h[4 * q + 2] = hv[q].z; h[4 * q + 3] = hv[q].w;
    }

    const float* W = ws + WS_W + TT * 16 * 16;
    float yv[16];
    #pragma unroll
    for (int i = 0; i < 16; ++i) {
        float acc = 0.0f;
        #pragma unroll
        for (int m = 0; m < 16; ++m) acc = fmaf(W[i * 16 + m], h[m], acc);
        yv[i] = acc;
    }

    __syncthreads();                      // xs tile ready

    const float* kv63 = ws + WS_KV + 63;  // kv63[q] = B^T A^q B
    #pragma unroll
    for (int ss = 0; ss < (TT + 1) * 16; ++ss) {
        const float xv = xs[ss * 64 + dl];
        #pragma unroll
        for (int i = 0; i < 16; ++i) {
            if (TT * 16 + i >= ss)
                yv[i] = fmaf(kv63[TT * 16 + i - ss], xv, yv[i]);
        }
    }

    float* yp = y + ((size_t)(b * SEQL + j * CT + TT * 16)) * DMODEL + d;
    #pragma unroll
    for (int i = 0; i < 16; ++i) yp[(size_t)i * DMODEL] = yv[i];
}

__global__ __launch_bounds__(256, 4) void k3_output(const float* __restrict__ x,
                                                    const float* __restrict__ ws,
                                                    float* __restrict__ y) {
    __shared__ __align__(16) float xs[CT * 64];    // [sigma][dl], 16 KiB
    const int blk  = blockIdx.x;          // 2048 blocks
    const int b    = blk >> 9;
    const int j    = (blk >> 4) & 31;
    const int dblk = blk & 15;
    const int t    = threadIdx.x;
    const int tq   = t >> 6;              // tau quarter = wave index
    const int dl   = t & 63;
    const int d    = dblk * 64 + dl;

    {
        const float* xp = x + ((size_t)(b * SEQL + j * CT)) * DMODEL + dblk * 64;
        #pragma unroll
        for (int k = 0; k < 4; ++k) {
            const int f     = k * 256 + t;
            const int sigma = f >> 4;
            const int cc    = f & 15;
            *(float4*)(&xs[sigma * 64 + cc * 4]) =
                *(const float4*)(xp + (size_t)sigma * DMODEL + cc * 4);
        }
    }

    switch (tq) {                          // wave-uniform branch
        case 0: k3_body<0>(xs, ws, y, b, j, d, dl); break;
        case 1: k3_body<1>(xs, ws, y, b, j, d, dl); break;
        case 2: k3_body<2>(xs, ws, y, b, j, d, dl); break;
        default: k3_body<3>(xs, ws, y, b, j, d, dl); break;
    }
}

// ---------------------------------------------------------------------------
extern "C" void kernel_launch(void* const* d_in, const int* in_sizes, int n_in,
                              void* d_out, int out_size, void* d_ws, size_t ws_size,
                              hipStream_t stream) {
    (void)in_sizes; (void)n_in; (void)out_size; (void)ws_size;
    const float* x  = (const float*)d_in[0];
    const float* A  = (const float*)d_in[1];
    const float* Bv = (const float*)d_in[2];
    float* out = (float*)d_out;
    float* ws  = (float*)d_ws;

    k1_tables_chunkstate<<<512, 256, 0, stream>>>(x, A, Bv, ws);
    k2_carry<<<256, 256, 0, stream>>>(ws);
    k3_output<<<2048, 256, 0, stream>>>(x, ws, out);
}

// Round 8
// 120.229 us; speedup vs baseline: 1.0045x; 1.0045x over previous
//
#include <hip/hip_runtime.h>

// Problem constants
#define BATCH  4
#define SEQL   2048
#define DMODEL 1024
#define NST    16
#define CT     64            // chunk length
#define NCH    (SEQL / CT)   // 32 chunks

// ws layout (float offsets). ws_size = 256 MiB, we use ~16.8 MiB.
#define WS_P     0           // P[sigma][m]   = (A^(CT-1-sigma) B)[m]     : CT*16
#define WS_W     1024        // W[tau][m]     = (B^T A^(tau+1))[m]        : CT*16
#define WS_KV    2048        // kvext[127], kvext[63+d] = B^T A^d B, 0 for d<0
#define WS_APOW  2176        // Apow[m][k]    = (A^CT)[m][k]              : 256
#define WS_HIN   4096        // hin[b][j][d][m] = s_{j-1}                 : B*NCH*D*16
#define WS_CBUF  (WS_HIN + BATCH * NCH * DMODEL * 16)   // c[b][j][d][m]  : B*NCH*D*16

// ---------------------------------------------------------------------------
// Setup: block delta (0..64) computes A^delta in fp64 via binary powering,
// then emits its slice of the tables. (proven R0 version — keeping the
// separate launch: tables in GLOBAL let K1/K2/K3 read them via the scalar
// path; fusing tables into streaming kernels cost ~25 us in R7.)
// ---------------------------------------------------------------------------
__global__ __launch_bounds__(256) void setup_tables(const float* __restrict__ A,
                                                    const float* __restrict__ Bv,
                                                    float* __restrict__ ws) {
    __shared__ double buf0[256], buf1[256], buf2[256], buf3[256];
    __shared__ double bd[16], vtmp[16];
    double* S  = buf0;
    double* R  = buf1;
    double* Ta = buf2;
    double* Tb = buf3;
    const int t  = threadIdx.x;
    const int i  = t >> 4;
    const int kk = t & 15;
    const int delta = blockIdx.x;   // 0..64

    S[t] = (double)A[t];
    R[t] = (i == kk) ? 1.0 : 0.0;
    if (t < 16) bd[t] = (double)Bv[t];
    __syncthreads();

    for (int sb = 0; sb < 7; ++sb) {
        if ((delta >> sb) & 1) {
            double acc = 0.0;
            #pragma unroll
            for (int l = 0; l < 16; ++l) acc += R[i * 16 + l] * S[l * 16 + kk];
            Ta[t] = acc;
            __syncthreads();
            double* tmp = R; R = Ta; Ta = tmp;
        }
        if (sb < 6) {
            double acc = 0.0;
            #pragma unroll
            for (int l = 0; l < 16; ++l) acc += S[i * 16 + l] * S[l * 16 + kk];
            Tb[t] = acc;
            __syncthreads();
            double* tmp = S; S = Tb; Tb = tmp;
        }
    }
    // R now holds A^delta (fp64)

    if (delta < CT) {
        if (t < 16) {   // m = t : P[CT-1-delta][m] = (A^delta B)[m]
            double acc = 0.0;
            #pragma unroll
            for (int k = 0; k < 16; ++k) acc += R[t * 16 + k] * bd[k];
            ws[WS_P + (CT - 1 - delta) * 16 + t] = (float)acc;
            vtmp[t] = acc;
        }
        __syncthreads();
        if (t == 0) {   // k_delta = B^T A^delta B
            double kd = 0.0;
            for (int m = 0; m < 16; ++m) kd += bd[m] * vtmp[m];
            ws[WS_KV + 63 + delta] = (float)kd;
        }
    }
    if (delta >= 1 && t < 16) {   // W[delta-1][m] = sum_n B[n] (A^delta)[n][m]
        double acc = 0.0;
        #pragma unroll
        for (int n = 0; n < 16; ++n) acc += bd[n] * R[n * 16 + t];
        ws[WS_W + (delta - 1) * 16 + t] = (float)acc;
    }
    if (delta == CT) ws[WS_APOW + t] = (float)R[t];   // A^CT carry matrix
    if (delta == 0 && t < 63) ws[WS_KV + t] = 0.0f;   // zero-pad negative lags
}

// ---------------------------------------------------------------------------
// K1: full chunk state, 512 blocks (proven R0/R3 body). P is read from
// GLOBAL with wave-uniform addresses -> compiler emits s_loads (scalar
// path, free); x stream double-buffered 8-wide; NO LDS in the hot loop.
// c_j[m] = sum_{sigma} P[sigma][m] x[sigma]
// ---------------------------------------------------------------------------
__global__ __launch_bounds__(256) void k1_chunkstate(const float* __restrict__ x,
                                                     float* __restrict__ ws) {
    const int blk  = blockIdx.x;          // 512 blocks
    const int b    = blk >> 7;
    const int j    = (blk >> 2) & 31;
    const int dblk = blk & 3;
    const int d    = dblk * 256 + threadIdx.x;

    const float* P  = ws + WS_P;          // wave-uniform -> s_load
    const float* xp = x + ((size_t)(b * SEQL + j * CT)) * DMODEL + d;

    float c[16];
    #pragma unroll
    for (int m = 0; m < 16; ++m) c[m] = 0.0f;

    float xa[8], xb[8];
    #pragma unroll
    for (int s = 0; s < 8; ++s) xa[s] = xp[(size_t)s * DMODEL];

    #pragma unroll
    for (int g = 0; g < 8; ++g) {         // 8 batches of 8 sigma
        float* cur = (g & 1) ? xb : xa;
        float* nxt = (g & 1) ? xa : xb;
        if (g < 7) {
            #pragma unroll
            for (int s = 0; s < 8; ++s)
                nxt[s] = xp[(size_t)((g + 1) * 8 + s) * DMODEL];
        }
        #pragma unroll
        for (int s = 0; s < 8; ++s) {
            const int ss = g * 8 + s;
            #pragma unroll
            for (int m = 0; m < 16; ++m)
                c[m] = fmaf(P[ss * 16 + m], cur[s], c[m]);
        }
    }

    float4* outp = (float4*)(ws + WS_CBUF + (((size_t)(b * NCH + j) * DMODEL) + d) * 16);
    #pragma unroll
    for (int q = 0; q < 4; ++q)
        outp[q] = make_float4(c[4 * q], c[4 * q + 1], c[4 * q + 2], c[4 * q + 3]);
}

// ---------------------------------------------------------------------------
// K2: carry scan over chunks (proven body). Thread = (channel d, m).
// All 32 chunk partials prefetched upfront (independent, coalesced 1KB/blk),
// then the serial shfl chain runs from registers.
// s_j = Apow*s_{j-1} + c_j ; hin_j = s_{j-1}.
// ---------------------------------------------------------------------------
__global__ __launch_bounds__(256) void k2_carry(float* __restrict__ ws) {
    const int blk = blockIdx.x;           // 256 blocks
    const int b   = blk >> 6;
    const int d0  = (blk & 63) * 16;
    const int t   = threadIdx.x;
    const int m   = t & 15;
    const int ch  = t >> 4;
    const int d   = d0 + ch;
    const int laneBase = t & 48;          // 16-lane group base within wave

    const float* cbuf    = ws + WS_CBUF;
    const size_t base0   = (((size_t)(b * NCH) * DMODEL) + d) * 16 + m;
    const size_t jstride = (size_t)DMODEL * 16;

    float cpre[NCH];
    #pragma unroll
    for (int j = 0; j < NCH; ++j)
        cpre[j] = cbuf[base0 + (size_t)j * jstride];

    float Arow[16];
    #pragma unroll
    for (int k = 0; k < 16; ++k) Arow[k] = ws[WS_APOW + m * 16 + k];

    float* hin = ws + WS_HIN;
    float s = 0.0f;
    #pragma unroll
    for (int j = 0; j < NCH; ++j) {
        hin[base0 + (size_t)j * jstride] = s;
        float acc = cpre[j];
        #pragma unroll
        for (int k = 0; k < 16; ++k)
            acc = fmaf(Arow[k], __shfl(s, laneBase + k, 64), acc);
        s = acc;
    }
}

// ---------------------------------------------------------------------------
// K3: proven round-6 version, unchanged. 2048 blocks, (256,4) = 128-VGPR
// budget (NO spill — (256,8) forced a 64-VGPR cap and ~105 MB of scratch
// traffic), 16 KiB LDS tile, all 64 taus per tile.
//   y[tau] = W[tau].h_in + sum_{s<=tau} kv[tau-s] x[s]
// ---------------------------------------------------------------------------
template <int TT>
__device__ __forceinline__ void k3_body(const float* __restrict__ xs,
                                        const float* __restrict__ ws,
                                        float* __restrict__ y,
                                        int b, int j, int d, int dl) {
    const float* hinp = ws + WS_HIN + (((size_t)(b * NCH + j) * DMODEL) + d) * 16;
    float4 hv[4];
    #pragma unroll
    for (int q = 0; q < 4; ++q) hv[q] = ((const float4*)hinp)[q];

    float h[16];
    #pragma unroll
    for (int q = 0; q < 4; ++q) {
        h[4 * q]     = hv[q].x; h[4 * q + 1] = hv[q].y;
        h[4 * q + 2] = hv[q].z; h[4 * q + 3] = hv[q].w;
    }

    const float* W = ws + WS_W + TT * 16 * 16;
    float yv[16];
    #pragma unroll
    for (int i = 0; i < 16; ++i) {
        float acc = 0.0f;
        #pragma unroll
        for (int m = 0; m < 16; ++m) acc = fmaf(W[i * 16 + m], h[m], acc);
        yv[i] = acc;
    }

    __syncthreads();                      // xs tile ready

    const float* kv63 = ws + WS_KV + 63;  // kv63[q] = B^T A^q B
    #pragma unroll
    for (int ss = 0; ss < (TT + 1) * 16; ++ss) {
        const float xv = xs[ss * 64 + dl];
        #pragma unroll
        for (int i = 0; i < 16; ++i) {
            if (TT * 16 + i >= ss)
                yv[i] = fmaf(kv63[TT * 16 + i - ss], xv, yv[i]);
        }
    }

    float* yp = y + ((size_t)(b * SEQL + j * CT + TT * 16)) * DMODEL + d;
    #pragma unroll
    for (int i = 0; i < 16; ++i) yp[(size_t)i * DMODEL] = yv[i];
}

__global__ __launch_bounds__(256, 4) void k3_output(const float* __restrict__ x,
                                                    const float* __restrict__ ws,
                                                    float* __restrict__ y) {
    __shared__ __align__(16) float xs[CT * 64];    // [sigma][dl], 16 KiB
    const int blk  = blockIdx.x;          // 2048 blocks
    const int b    = blk >> 9;
    const int j    = (blk >> 4) & 31;
    const int dblk = blk & 15;
    const int t    = threadIdx.x;
    const int tq   = t >> 6;              // tau quarter = wave index
    const int dl   = t & 63;
    const int d    = dblk * 64 + dl;

    {
        const float* xp = x + ((size_t)(b * SEQL + j * CT)) * DMODEL + dblk * 64;
        #pragma unroll
        for (int k = 0; k < 4; ++k) {
            const int f     = k * 256 + t;
            const int sigma = f >> 4;
            const int cc    = f & 15;
            *(float4*)(&xs[sigma * 64 + cc * 4]) =
                *(const float4*)(xp + (size_t)sigma * DMODEL + cc * 4);
        }
    }

    switch (tq) {                          // wave-uniform branch
        case 0: k3_body<0>(xs, ws, y, b, j, d, dl); break;
        case 1: k3_body<1>(xs, ws, y, b, j, d, dl); break;
        case 2: k3_body<2>(xs, ws, y, b, j, d, dl); break;
        default: k3_body<3>(xs, ws, y, b, j, d, dl); break;
    }
}

// ---------------------------------------------------------------------------
extern "C" void kernel_launch(void* const* d_in, const int* in_sizes, int n_in,
                              void* d_out, int out_size, void* d_ws, size_t ws_size,
                              hipStream_t stream) {
    (void)in_sizes; (void)n_in; (void)out_size; (void)ws_size;
    const float* x  = (const float*)d_in[0];
    const float* A  = (const float*)d_in[1];
    const float* Bv = (const float*)d_in[2];
    float* out = (float*)d_out;
    float* ws  = (float*)d_ws;

    setup_tables<<<65, 256, 0, stream>>>(A, Bv, ws);
    k1_chunkstate<<<512, 256, 0, stream>>>(x, ws);
    k2_carry<<<256, 256, 0, stream>>>(ws);
    k3_output<<<2048, 256, 0, stream>>>(x, ws, out);
}

// Round 9
// 117.700 us; speedup vs baseline: 1.0261x; 1.0215x over previous
//
#include <hip/hip_runtime.h>

// Problem constants
#define BATCH  4
#define SEQL   2048
#define DMODEL 1024
#define NST    16
#define CT     64            // chunk length
#define NCH    (SEQL / CT)   // 32 chunks

// ws layout (float offsets). ws_size = 256 MiB, we use ~16.8 MiB.
#define WS_P     0           // P[sigma][m]   = (A^(CT-1-sigma) B)[m]     : CT*16
#define WS_W     1024        // W[tau][m]     = (B^T A^(tau+1))[m]        : CT*16
#define WS_KV    2048        // kvext[127], kvext[63+d] = B^T A^d B, 0 for d<0
#define WS_APOW  2176        // Apow[m][k]    = (A^CT)[m][k]              : 256
#define WS_HIN   4096        // hin[b][j][d][m] = s_{j-1}                 : B*NCH*D*16
#define WS_CBUF  (WS_HIN + BATCH * NCH * DMODEL * 16)   // c[b][j][d][m]  : B*NCH*D*16

// ---------------------------------------------------------------------------
// Setup: block delta (0..64) computes A^delta in fp64 via binary powering,
// then emits its slice of the tables. (proven R0 version; runs in the
// fill-shadow — its cost is hidden under the harness ws re-poison.)
// ---------------------------------------------------------------------------
__global__ __launch_bounds__(256) void setup_tables(const float* __restrict__ A,
                                                    const float* __restrict__ Bv,
                                                    float* __restrict__ ws) {
    __shared__ double buf0[256], buf1[256], buf2[256], buf3[256];
    __shared__ double bd[16], vtmp[16];
    double* S  = buf0;
    double* R  = buf1;
    double* Ta = buf2;
    double* Tb = buf3;
    const int t  = threadIdx.x;
    const int i  = t >> 4;
    const int kk = t & 15;
    const int delta = blockIdx.x;   // 0..64

    S[t] = (double)A[t];
    R[t] = (i == kk) ? 1.0 : 0.0;
    if (t < 16) bd[t] = (double)Bv[t];
    __syncthreads();

    for (int sb = 0; sb < 7; ++sb) {
        if ((delta >> sb) & 1) {
            double acc = 0.0;
            #pragma unroll
            for (int l = 0; l < 16; ++l) acc += R[i * 16 + l] * S[l * 16 + kk];
            Ta[t] = acc;
            __syncthreads();
            double* tmp = R; R = Ta; Ta = tmp;
        }
        if (sb < 6) {
            double acc = 0.0;
            #pragma unroll
            for (int l = 0; l < 16; ++l) acc += S[i * 16 + l] * S[l * 16 + kk];
            Tb[t] = acc;
            __syncthreads();
            double* tmp = S; S = Tb; Tb = tmp;
        }
    }
    // R now holds A^delta (fp64)

    if (delta < CT) {
        if (t < 16) {   // m = t : P[CT-1-delta][m] = (A^delta B)[m]
            double acc = 0.0;
            #pragma unroll
            for (int k = 0; k < 16; ++k) acc += R[t * 16 + k] * bd[k];
            ws[WS_P + (CT - 1 - delta) * 16 + t] = (float)acc;
            vtmp[t] = acc;
        }
        __syncthreads();
        if (t == 0) {   // k_delta = B^T A^delta B
            double kd = 0.0;
            for (int m = 0; m < 16; ++m) kd += bd[m] * vtmp[m];
            ws[WS_KV + 63 + delta] = (float)kd;
        }
    }
    if (delta >= 1 && t < 16) {   // W[delta-1][m] = sum_n B[n] (A^delta)[n][m]
        double acc = 0.0;
        #pragma unroll
        for (int n = 0; n < 16; ++n) acc += bd[n] * R[n * 16 + t];
        ws[WS_W + (delta - 1) * 16 + t] = (float)acc;
    }
    if (delta == CT) ws[WS_APOW + t] = (float)R[t];   // A^CT carry matrix
    if (delta == 0 && t < 63) ws[WS_KV + t] = 0.0f;   // zero-pad negative lags
}

// ---------------------------------------------------------------------------
// K1: full chunk state, 512 blocks (proven R0/R3 body). P via wave-uniform
// global reads -> scalar path; x stream double-buffered; no LDS.
// c_j[m] = sum_{sigma} P[sigma][m] x[sigma]
// ---------------------------------------------------------------------------
__global__ __launch_bounds__(256) void k1_chunkstate(const float* __restrict__ x,
                                                     float* __restrict__ ws) {
    const int blk  = blockIdx.x;          // 512 blocks
    const int b    = blk >> 7;
    const int j    = (blk >> 2) & 31;
    const int dblk = blk & 3;
    const int d    = dblk * 256 + threadIdx.x;

    const float* P  = ws + WS_P;          // wave-uniform -> s_load
    const float* xp = x + ((size_t)(b * SEQL + j * CT)) * DMODEL + d;

    float c[16];
    #pragma unroll
    for (int m = 0; m < 16; ++m) c[m] = 0.0f;

    float xa[8], xb[8];
    #pragma unroll
    for (int s = 0; s < 8; ++s) xa[s] = xp[(size_t)s * DMODEL];

    #pragma unroll
    for (int g = 0; g < 8; ++g) {         // 8 batches of 8 sigma
        float* cur = (g & 1) ? xb : xa;
        float* nxt = (g & 1) ? xa : xb;
        if (g < 7) {
            #pragma unroll
            for (int s = 0; s < 8; ++s)
                nxt[s] = xp[(size_t)((g + 1) * 8 + s) * DMODEL];
        }
        #pragma unroll
        for (int s = 0; s < 8; ++s) {
            const int ss = g * 8 + s;
            #pragma unroll
            for (int m = 0; m < 16; ++m)
                c[m] = fmaf(P[ss * 16 + m], cur[s], c[m]);
        }
    }

    float4* outp = (float4*)(ws + WS_CBUF + (((size_t)(b * NCH + j) * DMODEL) + d) * 16);
    #pragma unroll
    for (int q = 0; q < 4; ++q)
        outp[q] = make_float4(c[4 * q], c[4 * q + 1], c[4 * q + 2], c[4 * q + 3]);
}

// ---------------------------------------------------------------------------
// K2: carry scan over chunks (proven body). Thread = (channel d, m).
// s_j = Apow*s_{j-1} + c_j ; hin_j = s_{j-1}.
// ---------------------------------------------------------------------------
__global__ __launch_bounds__(256) void k2_carry(float* __restrict__ ws) {
    const int blk = blockIdx.x;           // 256 blocks
    const int b   = blk >> 6;
    const int d0  = (blk & 63) * 16;
    const int t   = threadIdx.x;
    const int m   = t & 15;
    const int ch  = t >> 4;
    const int d   = d0 + ch;
    const int laneBase = t & 48;          // 16-lane group base within wave

    const float* cbuf    = ws + WS_CBUF;
    const size_t base0   = (((size_t)(b * NCH) * DMODEL) + d) * 16 + m;
    const size_t jstride = (size_t)DMODEL * 16;

    float cpre[NCH];
    #pragma unroll
    for (int j = 0; j < NCH; ++j)
        cpre[j] = cbuf[base0 + (size_t)j * jstride];

    float Arow[16];
    #pragma unroll
    for (int k = 0; k < 16; ++k) Arow[k] = ws[WS_APOW + m * 16 + k];

    float* hin = ws + WS_HIN;
    float s = 0.0f;
    #pragma unroll
    for (int j = 0; j < NCH; ++j) {
        hin[base0 + (size_t)j * jstride] = s;
        float acc = cpre[j];
        #pragma unroll
        for (int k = 0; k < 16; ++k)
            acc = fmaf(Arow[k], __shfl(s, laneBase + k, 64), acc);
        s = acc;
    }
}

// ---------------------------------------------------------------------------
// K3 v4: no LDS, no barrier. 2048 blocks = (b, j, 64-channel slice); the 4
// waves of a block are the 4 tau-quarters and SHARE the same 16 KB x-tile +
// 4 KB hin slice through L1 (32 KB, fits). Each wave reads only its own
// triangle rows directly from global (L1/L2/L3-warm; 256 B coalesced per
// row), 8-deep double-buffered — R0's proven k3_body load pattern. Waves
// retire independently (no tail-wave barrier skew); (256,4) = 128-VGPR
// budget, ~70 used, no spill.
//   y[tau] = W[tau].h_in + sum_{s<=tau} kv[tau-s] x[s]
// ---------------------------------------------------------------------------
template <int TT>
__device__ __forceinline__ void k3_body(const float* __restrict__ x,
                                        const float* __restrict__ ws,
                                        float* __restrict__ y,
                                        int b, int j, int d) {
    constexpr int LIM = (TT + 1) * 16;    // triangle depth: 16/32/48/64
    const float* hinp = ws + WS_HIN + (((size_t)(b * NCH + j) * DMODEL) + d) * 16;
    const float* xp   = x + ((size_t)(b * SEQL + j * CT)) * DMODEL + d;

    // issue h_in loads and first x batch together
    float4 hv[4];
    #pragma unroll
    for (int q = 0; q < 4; ++q) hv[q] = ((const float4*)hinp)[q];
    float xa[8], xb[8];
    #pragma unroll
    for (int s = 0; s < 8; ++s) xa[s] = xp[(size_t)s * DMODEL];

    float h[16];
    #pragma unroll
    for (int q = 0; q < 4; ++q) {
        h[4 * q]     = hv[q].x; h[4 * q + 1] = hv[q].y;
        h[4 * q + 2] = hv[q].z; h[4 * q + 3] = hv[q].w;
    }

    // correction: yv[i] = W[16TT+i] . h_in  (W wave-uniform -> s_loads)
    const float* W = ws + WS_W + TT * 16 * 16;
    float yv[16];
    #pragma unroll
    for (int i = 0; i < 16; ++i) {
        float acc = 0.0f;
        #pragma unroll
        for (int m = 0; m < 16; ++m) acc = fmaf(W[i * 16 + m], h[m], acc);
        yv[i] = acc;
    }

    // causal triangle, 8-wide double-buffered global reads
    const float* kv63 = ws + WS_KV + 63;  // kv63[q] = B^T A^q B
    #pragma unroll
    for (int g = 0; g < LIM / 8; ++g) {
        float* cur = (g & 1) ? xb : xa;
        float* nxt = (g & 1) ? xa : xb;
        if (g + 1 < LIM / 8) {
            #pragma unroll
            for (int s = 0; s < 8; ++s)
                nxt[s] = xp[(size_t)((g + 1) * 8 + s) * DMODEL];
        }
        #pragma unroll
        for (int s = 0; s < 8; ++s) {
            const int ss = g * 8 + s;
            #pragma unroll
            for (int i = 0; i < 16; ++i) {
                if (TT * 16 + i >= ss)    // compile-time per (ss, i)
                    yv[i] = fmaf(kv63[TT * 16 + i - ss], cur[s], yv[i]);
            }
        }
    }

    float* yp = y + ((size_t)(b * SEQL + j * CT + TT * 16)) * DMODEL + d;
    #pragma unroll
    for (int i = 0; i < 16; ++i) yp[(size_t)i * DMODEL] = yv[i];
}

__global__ __launch_bounds__(256, 4) void k3_output(const float* __restrict__ x,
                                                    const float* __restrict__ ws,
                                                    float* __restrict__ y) {
    const int blk  = blockIdx.x;          // 2048 blocks
    const int b    = blk >> 9;
    const int j    = (blk >> 4) & 31;
    const int dblk = blk & 15;            // 16 slices of 64 channels
    const int t    = threadIdx.x;
    const int tq   = t >> 6;              // tau quarter = wave index
    const int dl   = t & 63;
    const int d    = dblk * 64 + dl;

    switch (tq) {                          // wave-uniform branch
        case 0: k3_body<0>(x, ws, y, b, j, d); break;
        case 1: k3_body<1>(x, ws, y, b, j, d); break;
        case 2: k3_body<2>(x, ws, y, b, j, d); break;
        default: k3_body<3>(x, ws, y, b, j, d); break;
    }
}

// ---------------------------------------------------------------------------
extern "C" void kernel_launch(void* const* d_in, const int* in_sizes, int n_in,
                              void* d_out, int out_size, void* d_ws, size_t ws_size,
                              hipStream_t stream) {
    (void)in_sizes; (void)n_in; (void)out_size; (void)ws_size;
    const float* x  = (const float*)d_in[0];
    const float* A  = (const float*)d_in[1];
    const float* Bv = (const float*)d_in[2];
    float* out = (float*)d_out;
    float* ws  = (float*)d_ws;

    setup_tables<<<65, 256, 0, stream>>>(A, Bv, ws);
    k1_chunkstate<<<512, 256, 0, stream>>>(x, ws);
    k2_carry<<<256, 256, 0, stream>>>(ws);
    k3_output<<<2048, 256, 0, stream>>>(x, ws, out);
}